// Round 6
// baseline (207.530 us; speedup 1.0000x reference)
//
#include <hip/hip_runtime.h>
#include <cstdint>
#include <cstddef>

// Problem constants
#define HW 512
#define NPIX (HW * HW)           // 262144 pixels per image
#define NIMG 16
#define NII 32                   // (input j, image n) pairs: ii = j*16 + n
#define CHUNKS 64
#define CHUNK_PIX 4096
#define IN_ELEMS (NIMG * NPIX)   // 4194304 per input
#define WPI 4096                 // u64 words per ii (512 rows * 8)

typedef unsigned long long u64;

// Workspace layout (bytes)
#define WS_PARTA 0u                      // 32*64 entries * 4 doubles = 65536
#define WS_ZM    65536u                  // 32 u64
#define WS_MSEL  98304u                  // selected marker bitmaps (1 MB)
#define WS_KSEL  (WS_MSEL + 1048576u)    // selected mask bitmaps (1 MB)
#define WS_ROUT  (WS_KSEL + 1048576u)    // reconstruction result (1 MB)

// f64 sigmoid rounded to f32 — EXACT round-1 numerics. Used ONLY in find_cut.
__device__ __forceinline__ float sigmoid_f32(float x) {
    return (float)(1.0 / (1.0 + exp(-(double)x)));
}

// Fast f64 sigmoid for STATS ONLY (proven in R5, absmax 0.0).
__device__ __forceinline__ float sigmoid_fast(float xf) {
    double x = (double)xf;
    double y = x * -1.4426950408889634074;     // log2(e)
    if (y > 1000.0)  return 0.0f;
    if (y < -1000.0) return 1.0f;
    double n = __builtin_rint(y);
    double t = (y - n) * 0.69314718055994530942;
    double p = 2.5052108385441718775e-8;
    p = __builtin_fma(p, t, 2.7557319223985890653e-7);
    p = __builtin_fma(p, t, 2.7557319223985892511e-6);
    p = __builtin_fma(p, t, 2.4801587301587301566e-5);
    p = __builtin_fma(p, t, 1.9841269841269841253e-4);
    p = __builtin_fma(p, t, 1.3888888888888889419e-3);
    p = __builtin_fma(p, t, 8.3333333333333332177e-3);
    p = __builtin_fma(p, t, 4.1666666666666664354e-2);
    p = __builtin_fma(p, t, 1.6666666666666665741e-1);
    p = __builtin_fma(p, t, 5.0e-1);
    p = __builtin_fma(p, t, 1.0);
    p = __builtin_fma(p, t, 1.0);
    long long bits = ((long long)n + 1023ll) << 52;
    double e = p * __longlong_as_double(bits);
    return (float)(1.0 / (1.0 + e));
}

// ---------------------------------------------------------------------------
// k1: single input pass — passthrough copy + f64 partials {sum,sumsq,cnt,max}.
// (unchanged from R5 — proven)
__global__ void k1_copy_stats(const float* __restrict__ A, const float* __restrict__ B,
                              float* __restrict__ out, double* __restrict__ partA) {
    int b = blockIdx.x;            // 0..2047
    int ii = b >> 6, chunk = b & 63;
    int j = ii >> 4, n = ii & 15;
    const float* src = (j == 0 ? A : B) + (size_t)n * NPIX + (size_t)chunk * CHUNK_PIX;
    float* dst = out + (size_t)j * IN_ELEMS + (size_t)n * NPIX + (size_t)chunk * CHUNK_PIX;

    double s = 0.0, sq = 0.0, cc = 0.0;
    float mx = -__builtin_inff();
#pragma unroll
    for (int p = 0; p < 4; ++p) {
        float4 v = *(const float4*)(src + p * 1024 + threadIdx.x * 4);
        *(float4*)(dst + p * 1024 + threadIdx.x * 4) = v;
        float xs[4] = {v.x, v.y, v.z, v.w};
#pragma unroll
        for (int q = 0; q < 4; ++q) {
            float img = sigmoid_fast(xs[q]);
            mx = fmaxf(mx, xs[q]);
            if (img > 0.0f) { double d = (double)img; s += d; sq += d * d; cc += 1.0; }
        }
    }
    __shared__ double sm[256], sv[256], sc[256];
    __shared__ float smx[256];
    sm[threadIdx.x] = s; sv[threadIdx.x] = sq; sc[threadIdx.x] = cc; smx[threadIdx.x] = mx;
    __syncthreads();
    for (int off = 128; off > 0; off >>= 1) {
        if (threadIdx.x < off) {
            sm[threadIdx.x] += sm[threadIdx.x + off];
            sv[threadIdx.x] += sv[threadIdx.x + off];
            sc[threadIdx.x] += sc[threadIdx.x + off];
            smx[threadIdx.x] = fmaxf(smx[threadIdx.x], smx[threadIdx.x + off]);
        }
        __syncthreads();
    }
    if (threadIdx.x == 0) {
        double* p = partA + (size_t)(ii * 64 + chunk) * 4;
        p[0] = sm[0]; p[1] = sv[0]; p[2] = sc[0]; p[3] = (double)smx[0];
    }
}

// ---------------------------------------------------------------------------
// cutoff bisection over ordered-f32 key space with the exact libm sigmoid
// (proven bit-exact R2-R5).
__device__ __forceinline__ float key_to_f32(unsigned k) {
    unsigned b = (k & 0x80000000u) ? (k ^ 0x80000000u) : ~k;
    return __uint_as_float(b);
}
__device__ float find_cut(double T) {
    if (!(1.0 > T)) return __uint_as_float(0x7F800000u);
    unsigned lo = 0x007FFFFFu;   // key(-inf)
    unsigned hi = 0xFF800000u;   // key(+inf)
    while (lo < hi) {
        unsigned mid = lo + ((hi - lo) >> 1);
        float x = key_to_f32(mid);
        float s32 = sigmoid_f32(x);
        if ((double)s32 > T) hi = mid; else lo = mid + 1;
    }
    return key_to_f32(lo);
}

// ---------------------------------------------------------------------------
// k2: per-block redundant cutoff computation (kS folded in, one less launch)
// + selected marker/mask bitmaps via ballots (R5 logic) + zm.
__global__ void k2_bits(const float* __restrict__ A, const float* __restrict__ B,
                        const double* __restrict__ partA,
                        u64* __restrict__ msel, u64* __restrict__ ksel,
                        u64* __restrict__ zm) {
    int b = blockIdx.x, ii = b >> 6, chunk = b & 63;
    int j = ii >> 4, n = ii & 15;
    const float* src = (j == 0 ? A : B) + (size_t)n * NPIX;
    int t = threadIdx.x, lane = t & 63, w = t >> 6;

    __shared__ double shst[4];     // mean, sd, cnt, max
    __shared__ float cs[4];
    __shared__ float cut2[2];

    if (t < 64) {
        const double* p = partA + (size_t)(ii * 64 + t) * 4;
        double s = p[0], sq = p[1], c = p[2], mx = p[3];
#pragma unroll
        for (int off = 32; off > 0; off >>= 1) {
            s  += __shfl_down(s,  (unsigned)off, 64);
            sq += __shfl_down(sq, (unsigned)off, 64);
            c  += __shfl_down(c,  (unsigned)off, 64);
            mx  = fmax(mx, __shfl_down(mx, (unsigned)off, 64));
        }
        if (t == 0) {
            double mean = 0.0, sd = 0.0;
            if (c > 0.0) {
                mean = s / c;
                double var = sq / c - mean * mean;
                if (var < 0.0) var = 0.0;
                sd = sqrt(var);
            }
            shst[0] = mean; shst[1] = sd; shst[2] = c; shst[3] = mx;
        }
    }
    __syncthreads();
    if (t < 4) {
        double mean = shst[0], sd = shst[1];
        double fac = (ii < 16) ? 2.0 : 4.0;
        double T = (t == 0) ? mean + fac * sd
                 : (t == 1) ? mean + 0.5 * fac * sd
                 : (t == 2) ? mean + 0.5 * sd
                 :            mean + 0.25 * sd;
        cs[t] = find_cut(T);
    }
    __syncthreads();
    if (t == 0) {
        float mxf = (float)shst[3];
        cut2[0] = (mxf >= cs[0]) ? cs[0] : cs[1];   // marker (empty-fallback via max)
        cut2[1] = (mxf >= cs[2]) ? cs[2] : cs[3];   // mask
        if (chunk == 0) zm[ii] = (shst[2] > 0.0) ? ~0ull : 0ull;
    }
    __syncthreads();
    float cM = cut2[0], cK = cut2[1];

#pragma unroll 4
    for (int i = 0; i < 16; ++i) {
        float x = src[chunk * CHUNK_PIX + i * 256 + t];
        u64 bM = __ballot(x >= cM);
        u64 bK = __ballot(x >= cK);
        if (lane == 0) {
            size_t g = (size_t)ii * WPI + (size_t)chunk * 64 + i * 4 + w;
            msel[g] = bM; ksel[g] = bK;
        }
    }
}

// ---------------------------------------------------------------------------
// Masked horizontal fill of a 512-bit line to FIXPOINT in O(1) (proven R2-R5).
__device__ __forceinline__ void hfill8(u64* x, const u64* k) {
    u64 c = 0;
#pragma unroll
    for (int w = 0; w < 8; ++w) {
        u64 a = k[w], g = x[w];
        u64 t1 = a + g;  u64 c1 = (u64)(t1 < a);
        u64 t2 = t1 + c; u64 c2 = (u64)(t2 < t1);
        c = c1 | c2;
        x[w] = (~t2 | g) & a;
    }
    c = 0;
#pragma unroll
    for (int w = 7; w >= 0; --w) {
        u64 a = __brevll(k[w]), g = __brevll(x[w]);
        u64 t1 = a + g;  u64 c1 = (u64)(t1 < a);
        u64 t2 = t1 + c; u64 c2 = (u64)(t2 < t1);
        c = c1 | c2;
        x[w] = __brevll((~t2 | g) & a);
    }
}

// 64x64 bit-matrix transpose across a wave: lane i holds row i (one u64).
// Butterfly: at step s, lanes exchange with lane^s and swap s-bit sub-blocks.
// Verified: out[i] bit j = in[j] bit i (2x2 base case + quadrant recursion).
__device__ __forceinline__ u64 tr64(u64 x, int lane) {
    const u64 MS[6] = { 0x00000000FFFFFFFFull, 0x0000FFFF0000FFFFull,
                        0x00FF00FF00FF00FFull, 0x0F0F0F0F0F0F0F0Full,
                        0x3333333333333333ull, 0x5555555555555555ull };
#pragma unroll
    for (int i = 0; i < 6; ++i) {
        int s = 32 >> i;
        u64 m = MS[i];
        u64 y = __shfl_xor(x, s, 64);
        u64 a = (x & m) | ((y & m) << s);      // (lane & s) == 0 case
        u64 bq = (x & ~m) | ((y & ~m) >> s);   // (lane & s) != 0 case
        x = (lane & s) ? bq : a;
    }
    return x;
}

// In-place transpose of a 512x512 bitmap held word-interleaved in LDS
// (BUF[w*512 + row]). Tile (I,J) = rows 64I+i, word J at BUF[J*512+64I+i].
// Out tile (I,J) = tr64(src tile (J,I)); waves handle disjoint tile pairs.
__device__ void transpose512(u64* BUF, int t) {
    int lane = t & 63, wv = t >> 6;   // 8 waves
    int c = 0;
#pragma unroll
    for (int I = 0; I < 8; ++I) {
#pragma unroll
        for (int J = I; J < 8; ++J) {
            if ((c & 7) == wv) {
                if (I == J) {
                    u64 v = BUF[J * 512 + 64 * I + lane];
                    v = tr64(v, lane);
                    BUF[J * 512 + 64 * I + lane] = v;
                } else {
                    u64 a = BUF[J * 512 + 64 * I + lane];   // tile (I,J)
                    u64 b = BUF[I * 512 + 64 * J + lane];   // tile (J,I)
                    a = tr64(a, lane);
                    b = tr64(b, lane);
                    BUF[J * 512 + 64 * I + lane] = b;       // (I,J) <- T(J,I)
                    BUF[I * 512 + 64 * J + lane] = a;       // (J,I) <- T(I,J)
                }
            }
            ++c;
        }
    }
}

// ---------------------------------------------------------------------------
// k3: morphological reconstruction by alternating directional fixpoint fills.
// One block per ii, 512 threads, bitmap in 32 KB LDS (word-interleaved).
// Phase = in-place bit-transpose + hfill8 along the new orientation (mask held
// in registers for both orientations). Each phase reaches a full directional
// fixpoint, so iterations ~= geodesic turn count (<10 typ.) instead of the
// ~100+ row-steps of the Jacobi version. Terminates when a phase adds nothing
// (the other direction was already at fixpoint) -> same fixpoint as reference.
__global__ __launch_bounds__(512) void k3_flood(const u64* __restrict__ msel,
                                                const u64* __restrict__ ksel,
                                                u64* __restrict__ rout) {
    int ii = blockIdx.x, t = threadIdx.x;
    __shared__ u64 BUF[WPI];               // 32 KB
    const u64* M = msel + (size_t)ii * WPI;
    const u64* K = ksel + (size_t)ii * WPI;

    u64 kr[8], kc[8], r[8];
#pragma unroll
    for (int w = 0; w < 8; ++w) {
        kr[w] = K[(size_t)t * 8 + w];      // mask, row-orientation (row t)
        BUF[w * 512 + t] = kr[w];
    }
    __syncthreads();
    transpose512(BUF, t);                  // K^T
    __syncthreads();
#pragma unroll
    for (int w = 0; w < 8; ++w) kc[w] = BUF[w * 512 + t];  // mask, col-orientation
    __syncthreads();                       // all kc reads done before overwrite

#pragma unroll
    for (int w = 0; w < 8; ++w) r[w] = M[(size_t)t * 8 + w] & kr[w];  // marker ⊆ mask
    hfill8(r, kr);                         // initial horizontal fixpoint
#pragma unroll
    for (int w = 0; w < 8; ++w) BUF[w * 512 + t] = r[w];

    int orient = 0;                        // 0 = row-major, 1 = col-major
    for (int ph = 0; ph < 1200; ++ph) {
        __syncthreads();                   // fill writes visible to transpose
        transpose512(BUF, t);
        orient ^= 1;
        __syncthreads();                   // transpose writes visible to fill
        u64 rr[8], d = 0;
#pragma unroll
        for (int w = 0; w < 8; ++w) rr[w] = BUF[w * 512 + t];
        u64 old[8];
#pragma unroll
        for (int w = 0; w < 8; ++w) old[w] = rr[w];
        hfill8(rr, orient ? kc : kr);
#pragma unroll
        for (int w = 0; w < 8; ++w) {
            d |= rr[w] ^ old[w];
            BUF[w * 512 + t] = rr[w];
        }
        if (!__syncthreads_or(d != 0ull ? 1 : 0)) break;
    }

    if (orient == 1) {                     // return to row-major for output
        __syncthreads();
        transpose512(BUF, t);
        __syncthreads();
    }
    // word-interleaved output rout[ii*WPI + w*512 + row]
#pragma unroll
    for (int w = 0; w < 8; ++w)
        rout[(size_t)ii * WPI + (size_t)w * 512 + t] = BUF[w * 512 + t];
}

// ---------------------------------------------------------------------------
// k4: fused output = OR of the two reconstructions (masked by cnt>0), f32 0/1.
// (unchanged from R5 — proven; rout word-interleaved idx = w*512 + row)
__global__ void k4_fuse(const u64* __restrict__ rout,
                        const u64* __restrict__ zm,
                        float* __restrict__ out) {
    size_t gid = (size_t)blockIdx.x * blockDim.x + threadIdx.x;
    size_t p = gid * 4;
    int n = (int)(p >> 18);
    int e = (int)(p & (NPIX - 1));
    size_t gw = (size_t)(((e >> 6) & 7) * HW + (e >> 9));
    u64 w = (rout[(size_t)n * WPI + gw] & zm[n])
          | (rout[(size_t)(16 + n) * WPI + gw] & zm[16 + n]);
    int sh = e & 63;
    float4 v;
    v.x = ((w >> sh) & 1ull)       ? 1.0f : 0.0f;
    v.y = ((w >> (sh + 1)) & 1ull) ? 1.0f : 0.0f;
    v.z = ((w >> (sh + 2)) & 1ull) ? 1.0f : 0.0f;
    v.w = ((w >> (sh + 3)) & 1ull) ? 1.0f : 0.0f;
    *(float4*)(out + 2 * (size_t)IN_ELEMS + p) = v;
}

extern "C" void kernel_launch(void* const* d_in, const int* in_sizes, int n_in,
                              void* d_out, int out_size, void* d_ws, size_t ws_size,
                              hipStream_t stream) {
    const float* A = (const float*)d_in[0];
    const float* B = (const float*)d_in[1];
    float* out = (float*)d_out;
    char* ws = (char*)d_ws;

    double* partA = (double*)(ws + WS_PARTA);
    u64*    zm    = (u64*)(ws + WS_ZM);
    u64*    msel  = (u64*)(ws + WS_MSEL);
    u64*    ksel  = (u64*)(ws + WS_KSEL);
    u64*    rout  = (u64*)(ws + WS_ROUT);

    k1_copy_stats<<<NII * CHUNKS, 256, 0, stream>>>(A, B, out, partA);
    k2_bits<<<NII * CHUNKS, 256, 0, stream>>>(A, B, partA, msel, ksel, zm);
    k3_flood<<<NII, 512, 0, stream>>>(msel, ksel, rout);
    k4_fuse<<<4096, 256, 0, stream>>>(rout, zm, out);
}

// Round 7
// 141.489 us; speedup vs baseline: 1.4668x; 1.4668x over previous
//
#include <hip/hip_runtime.h>
#include <cstdint>
#include <cstddef>

// Problem constants
#define HW 512
#define NPIX (HW * HW)           // 262144 pixels per image
#define NIMG 16
#define NII 32                   // (input j, image n) pairs: ii = j*16 + n
#define CHUNKS 64
#define CHUNK_PIX 4096
#define IN_ELEMS (NIMG * NPIX)   // 4194304 per input
#define WPI 4096                 // u64 words per ii (512 rows * 8)

typedef unsigned long long u64;

// Workspace layout (bytes)
#define WS_PARTA 0u                      // 32*64 entries * 4 doubles = 65536
#define WS_ZM    65536u                  // 32 u64
#define WS_MSEL  98304u                  // selected marker bitmaps (1 MB)
#define WS_KSEL  (WS_MSEL + 1048576u)    // selected mask bitmaps (1 MB)
#define WS_ROUT  (WS_KSEL + 1048576u)    // reconstruction result (1 MB)

// f64 sigmoid rounded to f32 — EXACT round-1 numerics. Used ONLY in find_cut.
__device__ __forceinline__ float sigmoid_f32(float x) {
    return (float)(1.0 / (1.0 + exp(-(double)x)));
}

// Fast f64 sigmoid for STATS ONLY. Poly exp (proven R5/R6, rel err ~1e-14) +
// rcp_f32-seeded Newton reciprocal (2 iters -> rel err ~1e-16, replacing the
// compiler's expensive f64 divide). Same 1e-14 numerical regime that produced
// absmax 0.0 in R5/R6. Guarded f64-div fallback for extreme args (never taken
// for randn inputs, |x| < ~7).
__device__ __forceinline__ float sigmoid_fast(float xf) {
    double x = (double)xf;
    double y = x * -1.4426950408889634074;     // log2(e)
    if (y > 1000.0)  return 0.0f;
    if (y < -1000.0) return 1.0f;
    double n = __builtin_rint(y);
    double t = (y - n) * 0.69314718055994530942;
    double p = 2.5052108385441718775e-8;
    p = __builtin_fma(p, t, 2.7557319223985890653e-7);
    p = __builtin_fma(p, t, 2.7557319223985892511e-6);
    p = __builtin_fma(p, t, 2.4801587301587301566e-5);
    p = __builtin_fma(p, t, 1.9841269841269841253e-4);
    p = __builtin_fma(p, t, 1.3888888888888889419e-3);
    p = __builtin_fma(p, t, 8.3333333333333332177e-3);
    p = __builtin_fma(p, t, 4.1666666666666664354e-2);
    p = __builtin_fma(p, t, 1.6666666666666665741e-1);
    p = __builtin_fma(p, t, 5.0e-1);
    p = __builtin_fma(p, t, 1.0);
    p = __builtin_fma(p, t, 1.0);
    long long bits = ((long long)n + 1023ll) << 52;
    double e = p * __longlong_as_double(bits);     // exp(-x)
    double d = 1.0 + e;
    if (y > 100.0 || y < -100.0)                   // (float)d could overflow f32
        return (float)(1.0 / d);                   // cold path, never for randn
    double r = (double)__builtin_amdgcn_rcpf((float)d);  // ~1e-7 seed
    r = r * (2.0 - d * r);                         // ~1e-14
    r = r * (2.0 - d * r);                         // ~1e-16 (f64-limited)
    return (float)r;
}

// ---------------------------------------------------------------------------
// k1: single input pass — passthrough copy + f64 partials {sum,sumsq,cnt,max}.
__global__ void k1_copy_stats(const float* __restrict__ A, const float* __restrict__ B,
                              float* __restrict__ out, double* __restrict__ partA) {
    int b = blockIdx.x;            // 0..2047
    int ii = b >> 6, chunk = b & 63;
    int j = ii >> 4, n = ii & 15;
    const float* src = (j == 0 ? A : B) + (size_t)n * NPIX + (size_t)chunk * CHUNK_PIX;
    float* dst = out + (size_t)j * IN_ELEMS + (size_t)n * NPIX + (size_t)chunk * CHUNK_PIX;

    double s = 0.0, sq = 0.0, cc = 0.0;
    float mx = -__builtin_inff();
#pragma unroll
    for (int p = 0; p < 4; ++p) {
        float4 v = *(const float4*)(src + p * 1024 + threadIdx.x * 4);
        *(float4*)(dst + p * 1024 + threadIdx.x * 4) = v;
        float xs[4] = {v.x, v.y, v.z, v.w};
#pragma unroll
        for (int q = 0; q < 4; ++q) {
            float img = sigmoid_fast(xs[q]);
            mx = fmaxf(mx, xs[q]);
            if (img > 0.0f) { double d = (double)img; s += d; sq += d * d; cc += 1.0; }
        }
    }
    __shared__ double sm[256], sv[256], sc[256];
    __shared__ float smx[256];
    sm[threadIdx.x] = s; sv[threadIdx.x] = sq; sc[threadIdx.x] = cc; smx[threadIdx.x] = mx;
    __syncthreads();
    for (int off = 128; off > 0; off >>= 1) {
        if (threadIdx.x < off) {
            sm[threadIdx.x] += sm[threadIdx.x + off];
            sv[threadIdx.x] += sv[threadIdx.x + off];
            sc[threadIdx.x] += sc[threadIdx.x + off];
            smx[threadIdx.x] = fmaxf(smx[threadIdx.x], smx[threadIdx.x + off]);
        }
        __syncthreads();
    }
    if (threadIdx.x == 0) {
        double* p = partA + (size_t)(ii * 64 + chunk) * 4;
        p[0] = sm[0]; p[1] = sv[0]; p[2] = sc[0]; p[3] = (double)smx[0];
    }
}

// ---------------------------------------------------------------------------
// cutoff bisection over ordered-f32 key space with the exact libm sigmoid
// (proven bit-exact R2-R6).
__device__ __forceinline__ float key_to_f32(unsigned k) {
    unsigned b = (k & 0x80000000u) ? (k ^ 0x80000000u) : ~k;
    return __uint_as_float(b);
}
__device__ float find_cut(double T) {
    if (!(1.0 > T)) return __uint_as_float(0x7F800000u);
    unsigned lo = 0x007FFFFFu;   // key(-inf)
    unsigned hi = 0xFF800000u;   // key(+inf)
    while (lo < hi) {
        unsigned mid = lo + ((hi - lo) >> 1);
        float x = key_to_f32(mid);
        float s32 = sigmoid_f32(x);
        if ((double)s32 > T) hi = mid; else lo = mid + 1;
    }
    return key_to_f32(lo);
}

// ---------------------------------------------------------------------------
// k2: per-block redundant cutoff computation + selected marker/mask bitmaps
// via ballots + zm. (unchanged from R6 — proven)
__global__ void k2_bits(const float* __restrict__ A, const float* __restrict__ B,
                        const double* __restrict__ partA,
                        u64* __restrict__ msel, u64* __restrict__ ksel,
                        u64* __restrict__ zm) {
    int b = blockIdx.x, ii = b >> 6, chunk = b & 63;
    int j = ii >> 4, n = ii & 15;
    const float* src = (j == 0 ? A : B) + (size_t)n * NPIX;
    int t = threadIdx.x, lane = t & 63, w = t >> 6;

    __shared__ double shst[4];     // mean, sd, cnt, max
    __shared__ float cs[4];
    __shared__ float cut2[2];

    if (t < 64) {
        const double* p = partA + (size_t)(ii * 64 + t) * 4;
        double s = p[0], sq = p[1], c = p[2], mx = p[3];
#pragma unroll
        for (int off = 32; off > 0; off >>= 1) {
            s  += __shfl_down(s,  (unsigned)off, 64);
            sq += __shfl_down(sq, (unsigned)off, 64);
            c  += __shfl_down(c,  (unsigned)off, 64);
            mx  = fmax(mx, __shfl_down(mx, (unsigned)off, 64));
        }
        if (t == 0) {
            double mean = 0.0, sd = 0.0;
            if (c > 0.0) {
                mean = s / c;
                double var = sq / c - mean * mean;
                if (var < 0.0) var = 0.0;
                sd = sqrt(var);
            }
            shst[0] = mean; shst[1] = sd; shst[2] = c; shst[3] = mx;
        }
    }
    __syncthreads();
    if (t < 4) {
        double mean = shst[0], sd = shst[1];
        double fac = (ii < 16) ? 2.0 : 4.0;
        double T = (t == 0) ? mean + fac * sd
                 : (t == 1) ? mean + 0.5 * fac * sd
                 : (t == 2) ? mean + 0.5 * sd
                 :            mean + 0.25 * sd;
        cs[t] = find_cut(T);
    }
    __syncthreads();
    if (t == 0) {
        float mxf = (float)shst[3];
        cut2[0] = (mxf >= cs[0]) ? cs[0] : cs[1];   // marker (empty-fallback via max)
        cut2[1] = (mxf >= cs[2]) ? cs[2] : cs[3];   // mask
        if (chunk == 0) zm[ii] = (shst[2] > 0.0) ? ~0ull : 0ull;
    }
    __syncthreads();
    float cM = cut2[0], cK = cut2[1];

#pragma unroll 4
    for (int i = 0; i < 16; ++i) {
        float x = src[chunk * CHUNK_PIX + i * 256 + t];
        u64 bM = __ballot(x >= cM);
        u64 bK = __ballot(x >= cK);
        if (lane == 0) {
            size_t g = (size_t)ii * WPI + (size_t)chunk * 64 + i * 4 + w;
            msel[g] = bM; ksel[g] = bK;
        }
    }
}

// ---------------------------------------------------------------------------
// Masked horizontal fill of a 512-bit line to FIXPOINT in O(1) (proven R2-R6).
__device__ __forceinline__ void hfill8(u64* x, const u64* k) {
    u64 c = 0;
#pragma unroll
    for (int w = 0; w < 8; ++w) {
        u64 a = k[w], g = x[w];
        u64 t1 = a + g;  u64 c1 = (u64)(t1 < a);
        u64 t2 = t1 + c; u64 c2 = (u64)(t2 < t1);
        c = c1 | c2;
        x[w] = (~t2 | g) & a;
    }
    c = 0;
#pragma unroll
    for (int w = 7; w >= 0; --w) {
        u64 a = __brevll(k[w]), g = __brevll(x[w]);
        u64 t1 = a + g;  u64 c1 = (u64)(t1 < a);
        u64 t2 = t1 + c; u64 c2 = (u64)(t2 < t1);
        c = c1 | c2;
        x[w] = __brevll((~t2 | g) & a);
    }
}

// ---------------------------------------------------------------------------
// k3: morphological reconstruction — free-running async Gauss-Seidel.
// 32 blocks x 512 threads; thread t owns row t (registers), image mirrored in
// LDS (word-interleaved R[w*512+row], conflict-free). Sweeps run WITHOUT
// barriers: neighbor reads race with neighbor writes, which is monotone-safe
// (bits only turn on; a torn b64 read is old ⊆ value ⊆ fixpoint, and anything
// absorbed is masked by k so stays ⊆ fixpoint). Rows that gain bits re-run the
// O(1) horizontal fixpoint (hfill8) and write back. Every 4 sweeps, one
// __syncthreads_or: exit only after a barrier-delimited window in which NO
// thread gained -> state is the true fixpoint (monotone + stable).
__global__ __launch_bounds__(512) void k3_flood(const u64* __restrict__ msel,
                                                const u64* __restrict__ ksel,
                                                u64* __restrict__ rout) {
    int ii = blockIdx.x, t = threadIdx.x;   // t = row index
    __shared__ u64 R[8 * HW];               // 32 KB
    const u64* M = msel + (size_t)ii * WPI;
    const u64* K = ksel + (size_t)ii * WPI;

    u64 r[8], k[8];
#pragma unroll
    for (int w = 0; w < 8; ++w) {
        k[w] = K[(size_t)t * 8 + w];
        r[w] = M[(size_t)t * 8 + w] & k[w];   // marker ⊆ mask (Tm >= Tk always)
    }
    hfill8(r, k);                              // initial horizontal fixpoint
#pragma unroll
    for (int w = 0; w < 8; ++w) R[w * HW + t] = r[w];
    __syncthreads();

    for (int round = 0; round < 256; ++round) {   // 256*4 = 1024 sweeps max
        u64 gained = 0;
#pragma unroll 1
        for (int sweep = 0; sweep < 4; ++sweep) {
            u64 diff = 0;
#pragma unroll
            for (int w = 0; w < 8; ++w) {
                u64 nb = (t > 0      ? R[w * HW + (t - 1)] : 0ull)
                       | (t < HW - 1 ? R[w * HW + (t + 1)] : 0ull);
                u64 g = nb & k[w] & ~r[w];
                r[w] |= g; diff |= g;
            }
            if (diff) {        // uniform-false waves skip (s_cbranch_execz)
                hfill8(r, k);
#pragma unroll
                for (int w = 0; w < 8; ++w) R[w * HW + t] = r[w];
                gained |= diff;
            }
            asm volatile("" ::: "memory");   // force LDS re-read next sweep
        }
        if (!__syncthreads_or(gained != 0ull ? 1 : 0)) break;
    }

    // word-interleaved output: per w, 64 lanes store 512 contiguous bytes
#pragma unroll
    for (int w = 0; w < 8; ++w)
        rout[(size_t)ii * WPI + (size_t)w * HW + t] = r[w];
}

// ---------------------------------------------------------------------------
// k4: fused output = OR of the two reconstructions (masked by cnt>0), f32 0/1.
// (unchanged — proven; rout word-interleaved idx = w*512 + row)
__global__ void k4_fuse(const u64* __restrict__ rout,
                        const u64* __restrict__ zm,
                        float* __restrict__ out) {
    size_t gid = (size_t)blockIdx.x * blockDim.x + threadIdx.x;
    size_t p = gid * 4;
    int n = (int)(p >> 18);
    int e = (int)(p & (NPIX - 1));
    size_t gw = (size_t)(((e >> 6) & 7) * HW + (e >> 9));
    u64 w = (rout[(size_t)n * WPI + gw] & zm[n])
          | (rout[(size_t)(16 + n) * WPI + gw] & zm[16 + n]);
    int sh = e & 63;
    float4 v;
    v.x = ((w >> sh) & 1ull)       ? 1.0f : 0.0f;
    v.y = ((w >> (sh + 1)) & 1ull) ? 1.0f : 0.0f;
    v.z = ((w >> (sh + 2)) & 1ull) ? 1.0f : 0.0f;
    v.w = ((w >> (sh + 3)) & 1ull) ? 1.0f : 0.0f;
    *(float4*)(out + 2 * (size_t)IN_ELEMS + p) = v;
}

extern "C" void kernel_launch(void* const* d_in, const int* in_sizes, int n_in,
                              void* d_out, int out_size, void* d_ws, size_t ws_size,
                              hipStream_t stream) {
    const float* A = (const float*)d_in[0];
    const float* B = (const float*)d_in[1];
    float* out = (float*)d_out;
    char* ws = (char*)d_ws;

    double* partA = (double*)(ws + WS_PARTA);
    u64*    zm    = (u64*)(ws + WS_ZM);
    u64*    msel  = (u64*)(ws + WS_MSEL);
    u64*    ksel  = (u64*)(ws + WS_KSEL);
    u64*    rout  = (u64*)(ws + WS_ROUT);

    k1_copy_stats<<<NII * CHUNKS, 256, 0, stream>>>(A, B, out, partA);
    k2_bits<<<NII * CHUNKS, 256, 0, stream>>>(A, B, partA, msel, ksel, zm);
    k3_flood<<<NII, 512, 0, stream>>>(msel, ksel, rout);
    k4_fuse<<<4096, 256, 0, stream>>>(rout, zm, out);
}